// Round 9
// baseline (314.148 us; speedup 1.0000x reference)
//
#include <hip/hip_runtime.h>

typedef __bf16 bf16_t;
typedef __bf16 bf16x8 __attribute__((ext_vector_type(8)));
typedef __bf16 bf16x4 __attribute__((ext_vector_type(4)));
typedef float f32x4 __attribute__((ext_vector_type(4)));

static constexpr int Bb = 4, Hh = 12, Nn = 1024, Cc = 768, HD = 64;
static constexpr int OUT0 = Bb * Nn * Cc;  // 3145728 floats

#define GLD16(gp, lp)                                                       \
  __builtin_amdgcn_global_load_lds(                                         \
      (const __attribute__((address_space(1))) unsigned int*)(gp),          \
      (__attribute__((address_space(3))) unsigned int*)(lp), 16, 0, 0)

// ---------------- convert fp32 -> bf16 (x, qkv_w, proj_w) ----------------
__global__ __launch_bounds__(256) void convert_all(
    const float* __restrict__ x, const float* __restrict__ qw, const float* __restrict__ pw,
    bf16_t* __restrict__ xb, bf16_t* __restrict__ qwb, bf16_t* __restrict__ pwb) {
  const int NX = (Bb * Nn * Cc) / 4;  // 786432 float4s
  const int NQ = (3 * Cc * Cc) / 4;   // 442368
  int i = blockIdx.x * 256 + threadIdx.x;
  const float4* src;
  bf16_t* dst;
  int off;
  if (i < NX) { src = (const float4*)x; dst = xb; off = i; }
  else if (i < NX + NQ) { src = (const float4*)qw; dst = qwb; off = i - NX; }
  else { src = (const float4*)pw; dst = pwb; off = i - NX - NQ; }
  float4 v = src[off];
  bf16x4 o;
  o[0] = (bf16_t)v.x; o[1] = (bf16_t)v.y; o[2] = (bf16_t)v.z; o[3] = (bf16_t)v.w;
  *(bf16x4*)(dst + (size_t)off * 4) = o;
}

// ---------------- qkv GEMM: 128x128 tile, global_load_lds staging --------
// C[m,c] = x[m,:] . qkv_w[c,:]; epilogue scatters to q, k, vT (bf16).
__global__ __launch_bounds__(256) void gemm_qkv(
    const bf16_t* __restrict__ A, const bf16_t* __restrict__ Bm,
    bf16_t* __restrict__ q_bf, bf16_t* __restrict__ k_bf, bf16_t* __restrict__ vT_bf) {
  __shared__ bf16_t As[128 * 32];  // linear (global_load_lds requirement)
  __shared__ bf16_t Bs[128 * 32];
  const int tid = threadIdx.x;
  const int lane = tid & 63;
  const int w = tid >> 6;
  const int wr = w >> 1, wc = w & 1;
  const int g = lane >> 4, r = lane & 15;
  const int m0 = (blockIdx.x / 18) << 7;
  const int n0 = (blockIdx.x % 18) << 7;

  const f32x4 fz = {0.f, 0.f, 0.f, 0.f};
  f32x4 acc[4][4];
#pragma unroll
  for (int i = 0; i < 4; i++)
#pragma unroll
    for (int j = 0; j < 4; j++) acc[i][j] = fz;

  for (int k0 = 0; k0 < 768; k0 += 32) {
    // wave w stages rows [32w,32w+32) of A and B; linear LDS = base+lane*16
#pragma unroll
    for (int c = 0; c < 2; c++) {
      int row = w * 32 + c * 16 + (lane >> 2);
      int kof = (lane & 3) << 3;
      GLD16(&A[(size_t)(m0 + row) * 768 + k0 + kof], (char*)As + w * 2048 + c * 1024);
      GLD16(&Bm[(size_t)(n0 + row) * 768 + k0 + kof], (char*)Bs + w * 2048 + c * 1024);
    }
    __syncthreads();
    bf16x8 af[4], bfv[4];
#pragma unroll
    for (int i = 0; i < 4; i++) af[i] = *(const bf16x8*)&As[(wr * 64 + i * 16 + r) * 32 + g * 8];
#pragma unroll
    for (int j = 0; j < 4; j++) bfv[j] = *(const bf16x8*)&Bs[(wc * 64 + j * 16 + r) * 32 + g * 8];
#pragma unroll
    for (int i = 0; i < 4; i++)
#pragma unroll
      for (int j = 0; j < 4; j++)
        acc[i][j] = __builtin_amdgcn_mfma_f32_16x16x32_bf16(af[i], bfv[j], acc[i][j], 0, 0, 0);
    __syncthreads();
  }

#pragma unroll
  for (int i = 0; i < 4; i++) {
#pragma unroll
    for (int j = 0; j < 4; j++) {
      int c = n0 + wc * 64 + j * 16 + r;
#pragma unroll
      for (int e = 0; e < 4; e++) {
        int mrow = m0 + wr * 64 + i * 16 + g * 4 + e;
        float val = acc[i][j][e];
        int which = c / 768;
        int cc = c - which * 768;
        int h = cc >> 6, d = cc & 63;
        int b = mrow >> 10, n = mrow & 1023;
        size_t bh = (size_t)(b * Hh + h);
        if (which == 0)      q_bf[(bh * Nn + n) * HD + d] = (bf16_t)val;
        else if (which == 1) k_bf[(bh * Nn + n) * HD + d] = (bf16_t)val;
        else                 vT_bf[(bh * HD + d) * Nn + n] = (bf16_t)val;
      }
    }
  }
}

// ---------------- per-(b,h,n) bias MLP -> {1+b0, b1, -b2/N, 0} -----------
__global__ __launch_bounds__(256) void bias_mlp(
    const bf16_t* __restrict__ qb, const bf16_t* __restrict__ kb,
    const float* __restrict__ w1, const float* __restrict__ b1,
    const float* __restrict__ w2, const float* __restrict__ b2,
    float* __restrict__ bias4) {
  __shared__ float w1s[32 * 129];
  __shared__ float qks[8][128];
  __shared__ float h1s[8][32];
  const int t = threadIdx.x;
#pragma unroll
  for (int p = 0; p < 16; p++) {
    int idx = p * 256 + t;
    w1s[(idx >> 7) * 129 + (idx & 127)] = w1[idx];
  }
  const int rl = t >> 5, u = t & 31;
  const int rowg = blockIdx.x * 8 + rl;
  {
    int i4 = u * 4;
    const bf16_t* src = (i4 < 64) ? (qb + (size_t)rowg * HD + i4)
                                  : (kb + (size_t)rowg * HD + (i4 - 64));
    bf16x4 vv = *(const bf16x4*)src;
#pragma unroll
    for (int z = 0; z < 4; z++) qks[rl][i4 + z] = (float)vv[z];
  }
  __syncthreads();
  float accv = b1[u];
#pragma unroll 8
  for (int i = 0; i < 128; i++) accv += qks[rl][i] * w1s[u * 129 + i];
  h1s[rl][u] = fmaxf(accv, 0.f);
  __syncthreads();
  if (u < 4) {
    float outv = 0.f;
    if (u < 3) {
      float s = b2[u];
#pragma unroll
      for (int j = 0; j < 32; j++) s += w2[u * 32 + j] * h1s[rl][j];
      float v = fabsf(s);
      outv = (u == 0) ? (1.f + v) : ((u == 1) ? v : -v * (1.f / (float)Nn));
    }
    bias4[(size_t)rowg * 4 + u] = outv;
  }
}

// ---------------- vsum[b][h*64+d] = sum_n v[b,h,n,d] (one wave each) -----
__global__ __launch_bounds__(256) void vsum_k(
    const bf16_t* __restrict__ vT, float* __restrict__ vsum) {
  const int wid = (blockIdx.x * 256 + threadIdx.x) >> 6;  // 0..3071
  const int lane = threadIdx.x & 63;
  const int b = wid / 768, c = wid % 768;
  const int h = c >> 6, d = c & 63;
  const bf16_t* vp = vT + ((size_t)((b * Hh + h) * HD + d)) * Nn + lane * 16;
  bf16x8 v0 = *(const bf16x8*)vp;
  bf16x8 v1 = *(const bf16x8*)(vp + 8);
  float s = 0.f;
#pragma unroll
  for (int j = 0; j < 8; j++) s += (float)v0[j] + (float)v1[j];
#pragma unroll
  for (int sh = 1; sh < 64; sh <<= 1) s += __shfl_xor(s, sh, 64);
  if (lane == 0) vsum[wid] = s;
}

// ---------------- flash_pv: QK^T -> softmax -> cur + blended PV ----------
// 256 thr (4 waves) per 16-row tile. Wave w: QK cols [256w,+256) in acc[16].
// P -> LDS bf16 with double-XOR swizzle (row&7 ^ col-chunk&7). Then:
//   (a) coalesced cur write (lane i -> float4 @ 4i, from ds_read_b64)
//   (b) PV with pre-blended A = (1+b0)*P + b1*prev (per-row coefs; prev
//       loads are per-lane float4, double-buffered 2-deep, static indices)
// O1 = blended attn @ v (minus the vsum rank-1 term, folded into proj).
__global__ __launch_bounds__(256, 4) void flash_pv(
    const bf16_t* __restrict__ qb, const bf16_t* __restrict__ kb,
    const bf16_t* __restrict__ vT, const float* __restrict__ prev,
    const float* __restrict__ bias4, float* __restrict__ cur,
    bf16_t* __restrict__ O1) {
  __shared__ char Plb[16 * 2048];  // 16 rows x 1024 bf16, swizzled
  __shared__ float redmax[16][4];
  __shared__ float redsum[16][4];
  const int bid = blockIdx.x;
  const int tile = (bid & 7) * 384 + (bid >> 3);  // XCD-bijective (3072%8==0)
  const int bh = tile >> 6, mt = tile & 63;
  const int tid = threadIdx.x;
  const int lane = tid & 63, w = tid >> 6;
  const int g = lane >> 4, r = lane & 15;
  const int row0 = mt << 4;

  const bf16_t* qp = qb + ((size_t)bh * Nn + row0) * HD;
  const bf16_t* kp = kb + (size_t)bh * Nn * HD;
  const bf16_t* vp = vT + (size_t)bh * HD * Nn;
  bf16x8 a0 = *(const bf16x8*)&qp[r * HD + g * 8];
  bf16x8 a1 = *(const bf16x8*)&qp[r * HD + g * 8 + 32];
  const f32x4 fz = {0.f, 0.f, 0.f, 0.f};
  f32x4 acc[16];
#pragma unroll
  for (int t = 0; t < 16; t++) {
    int col = (w << 8) + (t << 4) + r;
    bf16x8 b0 = *(const bf16x8*)&kp[(size_t)col * HD + g * 8];
    bf16x8 b1 = *(const bf16x8*)&kp[(size_t)col * HD + g * 8 + 32];
    f32x4 z = __builtin_amdgcn_mfma_f32_16x16x32_bf16(a0, b0, fz, 0, 0, 0);
    acc[t] = __builtin_amdgcn_mfma_f32_16x16x32_bf16(a1, b1, z, 0, 0, 0);
  }
  const float scale = 0.125f;
  float mj[4] = {-3.0e38f, -3.0e38f, -3.0e38f, -3.0e38f};
#pragma unroll
  for (int t = 0; t < 16; t++)
#pragma unroll
    for (int e = 0; e < 4; e++) {
      acc[t][e] *= scale;
      mj[e] = fmaxf(mj[e], acc[t][e]);
    }
#pragma unroll
  for (int s = 1; s < 16; s <<= 1)
#pragma unroll
    for (int e = 0; e < 4; e++) mj[e] = fmaxf(mj[e], __shfl_xor(mj[e], s, 64));
  if (r == 0) {
#pragma unroll
    for (int e = 0; e < 4; e++) redmax[g * 4 + e][w] = mj[e];
  }
  __syncthreads();
  float rm[4];
#pragma unroll
  for (int e = 0; e < 4; e++) {
    float v = fmaxf(redmax[g * 4 + e][0], redmax[g * 4 + e][1]);
    rm[e] = fmaxf(v, fmaxf(redmax[g * 4 + e][2], redmax[g * 4 + e][3]));
  }
  float sj[4] = {0.f, 0.f, 0.f, 0.f};
#pragma unroll
  for (int t = 0; t < 16; t++)
#pragma unroll
    for (int e = 0; e < 4; e++) {
      float ev = __expf(acc[t][e] - rm[e]);
      acc[t][e] = ev;
      sj[e] += ev;
    }
#pragma unroll
  for (int s = 1; s < 16; s <<= 1)
#pragma unroll
    for (int e = 0; e < 4; e++) sj[e] += __shfl_xor(sj[e], s, 64);
  if (r == 0) {
#pragma unroll
    for (int e = 0; e < 4; e++) redsum[g * 4 + e][w] = sj[e];
  }
  __syncthreads();
  float inv[4];
#pragma unroll
  for (int e = 0; e < 4; e++)
    inv[e] = 1.f / (redsum[g * 4 + e][0] + redsum[g * 4 + e][1] +
                    redsum[g * 4 + e][2] + redsum[g * 4 + e][3]);
  // P -> LDS (bf16, double-XOR swizzle)
#pragma unroll
  for (int t = 0; t < 16; t++) {
    int col = (w << 8) + (t << 4) + r;
#pragma unroll
    for (int e = 0; e < 4; e++) {
      int row = g * 4 + e;
      int off = (row * 2048 + col * 2) ^ ((((row & 7) ^ ((col >> 6) & 7))) << 4);
      *(bf16_t*)(Plb + off) = (bf16_t)(acc[t][e] * inv[e]);
    }
  }
  __syncthreads();

  // ---- PV prefetch batches 0,1 (prev, per-lane rows) ----
  const float4 bvr = *(const float4*)&bias4[((size_t)bh * 1024 + row0 + r) * 4];
  const float b0c = bvr.x, b1c = bvr.y;
  const float* ppr = prev + (size_t)bh * Nn * Nn + (size_t)(row0 + r) * Nn;
  const bf16_t* vrow = vp + (size_t)((w << 4) + r) * Nn;
  float4 pf[2][4];
#pragma unroll
  for (int ks = 0; ks < 2; ks++) {
    pf[0][ks * 2]     = *(const float4*)&ppr[ks * 32 + g * 8];
    pf[0][ks * 2 + 1] = *(const float4*)&ppr[ks * 32 + g * 8 + 4];
    pf[1][ks * 2]     = *(const float4*)&ppr[64 + ks * 32 + g * 8];
    pf[1][ks * 2 + 1] = *(const float4*)&ppr[64 + ks * 32 + g * 8 + 4];
  }

  // ---- coalesced cur write (streams while prefetch in flight) ----
  {
    const int row = tid >> 4, c4 = (tid & 15) << 2;
    float* cw = cur + (size_t)bh * Nn * Nn + (size_t)(row0 + row) * Nn;
#pragma unroll
    for (int cc = 0; cc < 16; cc++) {
      int col = cc * 64 + c4;
      int off = (row * 2048 + col * 2) ^ ((((row & 7) ^ (cc & 7))) << 4);
      bf16x4 p4 = *(const bf16x4*)(Plb + off);
      float4 o;
      o.x = (float)p4[0]; o.y = (float)p4[1]; o.z = (float)p4[2]; o.w = (float)p4[3];
      *(float4*)&cw[col] = o;
    }
  }

  // ---- PV: 16 batches of 64 cols; A = b0c*P + b1c*prev ----
  f32x4 c0 = fz, c1 = fz, c2 = fz, c3 = fz;
#pragma unroll
  for (int b = 0; b < 16; b++) {
    float4 q0 = pf[b & 1][0], q1 = pf[b & 1][1];
    float4 q2 = pf[b & 1][2], q3 = pf[b & 1][3];
    if (b < 14) {
#pragma unroll
      for (int ks = 0; ks < 2; ks++) {
        pf[b & 1][ks * 2]     = *(const float4*)&ppr[(b + 2) * 64 + ks * 32 + g * 8];
        pf[b & 1][ks * 2 + 1] = *(const float4*)&ppr[(b + 2) * 64 + ks * 32 + g * 8 + 4];
      }
    }
#pragma unroll
    for (int ks = 0; ks < 2; ks++) {
      int k0 = b * 64 + ks * 32;
      int poff = (r * 2048 + (k0 + g * 8) * 2) ^ ((((r & 7) ^ (k0 >> 6 & 7))) << 4);
      bf16x8 pa = *(const bf16x8*)(Plb + poff);
      float4 qa = (ks == 0) ? q0 : q2;
      float4 qb2 = (ks == 0) ? q1 : q3;
      bf16x8 ab;
      ab[0] = (bf16_t)(b0c * (float)pa[0] + b1c * qa.x);
      ab[1] = (bf16_t)(b0c * (float)pa[1] + b1c * qa.y);
      ab[2] = (bf16_t)(b0c * (float)pa[2] + b1c * qa.z);
      ab[3] = (bf16_t)(b0c * (float)pa[3] + b1c * qa.w);
      ab[4] = (bf16_t)(b0c * (float)pa[4] + b1c * qb2.x);
      ab[5] = (bf16_t)(b0c * (float)pa[5] + b1c * qb2.y);
      ab[6] = (bf16_t)(b0c * (float)pa[6] + b1c * qb2.z);
      ab[7] = (bf16_t)(b0c * (float)pa[7] + b1c * qb2.w);
      bf16x8 vb = *(const bf16x8*)&vrow[k0 + g * 8];
      if (((b & 1) * 2 + ks) == 0) c0 = __builtin_amdgcn_mfma_f32_16x16x32_bf16(ab, vb, c0, 0, 0, 0);
      else if (((b & 1) * 2 + ks) == 1) c1 = __builtin_amdgcn_mfma_f32_16x16x32_bf16(ab, vb, c1, 0, 0, 0);
      else if (((b & 1) * 2 + ks) == 2) c2 = __builtin_amdgcn_mfma_f32_16x16x32_bf16(ab, vb, c2, 0, 0, 0);
      else c3 = __builtin_amdgcn_mfma_f32_16x16x32_bf16(ab, vb, c3, 0, 0, 0);
    }
  }
  f32x4 osum = (c0 + c1) + (c2 + c3);
  const int b = bh / Hh, h = bh % Hh;
#pragma unroll
  for (int e = 0; e < 4; e++) {
    int nrow = row0 + g * 4 + e;
    O1[((size_t)(b * Nn + nrow)) * Cc + h * HD + (w << 4) + r] = (bf16_t)osum[e];
  }
}

// ---------------- proj GEMM: A[row][c] = O1 + (-b2/N)*vsum ---------------
__global__ __launch_bounds__(256) void gemm_proj(
    const bf16_t* __restrict__ O1, const float* __restrict__ bias4,
    const float* __restrict__ vsum, const bf16_t* __restrict__ Bw,
    const float* __restrict__ pbias, float* __restrict__ outF) {
  __shared__ bf16_t As[128 * 40];
  __shared__ bf16_t Bs[128 * 40];
  const int tid = threadIdx.x, lane = tid & 63, w = tid >> 6;
  const int wr = w >> 1, wc = w & 1;
  const int g = lane >> 4, r = lane & 15;
  const int m0 = (blockIdx.x / 6) << 7;
  const int n0 = (blockIdx.x % 6) << 7;
  const f32x4 fz = {0.f, 0.f, 0.f, 0.f};
  f32x4 acc[4][4];
#pragma unroll
  for (int i = 0; i < 4; i++)
#pragma unroll
    for (int j = 0; j < 4; j++) acc[i][j] = fz;

  for (int k0 = 0; k0 < 768; k0 += 32) {
#pragma unroll
    for (int p = 0; p < 2; p++) {
      int idx = tid + (p << 8);
      int row = idx >> 2, kof = (idx & 3) << 3;
      int grow = m0 + row;
      int b = grow >> 10, n = grow & 1023;
      int c = k0 + kof, h = c >> 6;
      bf16x8 o1 = *(const bf16x8*)&O1[(size_t)grow * Cc + c];
      float bz = bias4[((size_t)(b * Hh + h) * Nn + n) * 4 + 2];
      float4 v0 = *(const float4*)&vsum[b * Cc + c];
      float4 v1 = *(const float4*)&vsum[b * Cc + c + 4];
      float vs[8] = {v0.x, v0.y, v0.z, v0.w, v1.x, v1.y, v1.z, v1.w};
      bf16x8 a;
#pragma unroll
      for (int j = 0; j < 8; j++)
        a[j] = (bf16_t)((float)o1[j] + bz * vs[j]);
      *(bf16x8*)&As[row * 40 + kof] = a;
      *(bf16x8*)&Bs[row * 40 + kof] = *(const bf16x8*)&Bw[(size_t)(n0 + row) * Cc + k0 + kof];
    }
    __syncthreads();
    bf16x8 af[4], bfv[4];
#pragma unroll
    for (int i = 0; i < 4; i++) af[i] = *(const bf16x8*)&As[(wr * 64 + i * 16 + r) * 40 + g * 8];
#pragma unroll
    for (int j = 0; j < 4; j++) bfv[j] = *(const bf16x8*)&Bs[(wc * 64 + j * 16 + r) * 40 + g * 8];
#pragma unroll
    for (int i = 0; i < 4; i++)
#pragma unroll
      for (int j = 0; j < 4; j++)
        acc[i][j] = __builtin_amdgcn_mfma_f32_16x16x32_bf16(af[i], bfv[j], acc[i][j], 0, 0, 0);
    __syncthreads();
  }
#pragma unroll
  for (int i = 0; i < 4; i++)
#pragma unroll
    for (int j = 0; j < 4; j++) {
      int c = n0 + wc * 64 + j * 16 + r;
#pragma unroll
      for (int e = 0; e < 4; e++) {
        int mrow = m0 + wr * 64 + i * 16 + g * 4 + e;
        outF[(size_t)mrow * Cc + c] = acc[i][j][e] + pbias[c];
      }
    }
}

// -------------------------------------------------------------------------
extern "C" void kernel_launch(void* const* d_in, const int* in_sizes, int n_in,
                              void* d_out, int out_size, void* d_ws, size_t ws_size,
                              hipStream_t stream) {
  const float* x      = (const float*)d_in[0];
  const float* prev   = (const float*)d_in[1];
  const float* qkv_w  = (const float*)d_in[2];
  const float* proj_w = (const float*)d_in[3];
  const float* proj_b = (const float*)d_in[4];
  const float* bp_w1  = (const float*)d_in[5];
  const float* bp_b1  = (const float*)d_in[6];
  const float* bp_w2  = (const float*)d_in[7];
  const float* bp_w2b = (const float*)d_in[8];

  float* out0 = (float*)d_out;
  float* cur  = out0 + OUT0;

  char* ws = (char*)d_ws;
  bf16_t* xb    = (bf16_t*)(ws + 0);          // dead after gemm_qkv -> O1
  bf16_t* O1b   = (bf16_t*)(ws + 0);          // 6291456
  bf16_t* qwb   = (bf16_t*)(ws + 6291456);    // dead after gemm_qkv -> vsum
  float*  vsum  = (float*)(ws + 6291456);     // 12288
  bf16_t* pwb   = (bf16_t*)(ws + 9830400);
  bf16_t* qbf   = (bf16_t*)(ws + 11010048);
  bf16_t* kbf   = (bf16_t*)(ws + 17301504);
  bf16_t* vtb   = (bf16_t*)(ws + 23592960);
  float*  bias4 = (float*)(ws + 29884416);    // 786432 -> end 30670848
  if (ws_size < 30670848) return;

  convert_all<<<5376, 256, 0, stream>>>(x, qkv_w, proj_w, xb, qwb, pwb);
  gemm_qkv<<<32 * 18, 256, 0, stream>>>(xb, qwb, qbf, kbf, vtb);
  bias_mlp<<<49152 / 8, 256, 0, stream>>>(qbf, kbf, bp_w1, bp_b1, bp_w2, bp_w2b, bias4);
  vsum_k<<<768, 256, 0, stream>>>(vtb, vsum);
  flash_pv<<<3072, 256, 0, stream>>>(qbf, kbf, vtb, prev, bias4, cur, O1b);
  gemm_proj<<<32 * 6, 256, 0, stream>>>(O1b, bias4, vsum, pwb, proj_b, out0);
}

// Round 10
// 240.923 us; speedup vs baseline: 1.3039x; 1.3039x over previous
//
#include <hip/hip_runtime.h>

typedef __bf16 bf16_t;
typedef __bf16 bf16x8 __attribute__((ext_vector_type(8)));
typedef __bf16 bf16x4 __attribute__((ext_vector_type(4)));
typedef float f32x4 __attribute__((ext_vector_type(4)));

static constexpr int Bb = 4, Hh = 12, Nn = 1024, Cc = 768, HD = 64;
static constexpr int OUT0 = Bb * Nn * Cc;  // 3145728 floats

#define GLD16(gp, lp)                                                       \
  __builtin_amdgcn_global_load_lds(                                         \
      (const __attribute__((address_space(1))) unsigned int*)(gp),          \
      (__attribute__((address_space(3))) unsigned int*)(lp), 16, 0, 0)

// ---------------- convert fp32 -> bf16 (x, qkv_w, proj_w) ----------------
__global__ __launch_bounds__(256) void convert_all(
    const float* __restrict__ x, const float* __restrict__ qw, const float* __restrict__ pw,
    bf16_t* __restrict__ xb, bf16_t* __restrict__ qwb, bf16_t* __restrict__ pwb) {
  const int NX = (Bb * Nn * Cc) / 4;  // 786432 float4s
  const int NQ = (3 * Cc * Cc) / 4;   // 442368
  int i = blockIdx.x * 256 + threadIdx.x;
  const float4* src;
  bf16_t* dst;
  int off;
  if (i < NX) { src = (const float4*)x; dst = xb; off = i; }
  else if (i < NX + NQ) { src = (const float4*)qw; dst = qwb; off = i - NX; }
  else { src = (const float4*)pw; dst = pwb; off = i - NX - NQ; }
  float4 v = src[off];
  bf16x4 o;
  o[0] = (bf16_t)v.x; o[1] = (bf16_t)v.y; o[2] = (bf16_t)v.z; o[3] = (bf16_t)v.w;
  *(bf16x4*)(dst + (size_t)off * 4) = o;
}

// ---------------- qkv GEMM: 128x128 tile, global_load_lds staging --------
__global__ __launch_bounds__(256) void gemm_qkv(
    const bf16_t* __restrict__ A, const bf16_t* __restrict__ Bm,
    bf16_t* __restrict__ q_bf, bf16_t* __restrict__ k_bf, bf16_t* __restrict__ vT_bf) {
  __shared__ bf16_t As[128 * 32];  // linear (global_load_lds requirement)
  __shared__ bf16_t Bs[128 * 32];
  const int tid = threadIdx.x;
  const int lane = tid & 63;
  const int w = tid >> 6;
  const int wr = w >> 1, wc = w & 1;
  const int g = lane >> 4, r = lane & 15;
  const int m0 = (blockIdx.x / 18) << 7;
  const int n0 = (blockIdx.x % 18) << 7;

  const f32x4 fz = {0.f, 0.f, 0.f, 0.f};
  f32x4 acc[4][4];
#pragma unroll
  for (int i = 0; i < 4; i++)
#pragma unroll
    for (int j = 0; j < 4; j++) acc[i][j] = fz;

  for (int k0 = 0; k0 < 768; k0 += 32) {
#pragma unroll
    for (int c = 0; c < 2; c++) {
      int row = w * 32 + c * 16 + (lane >> 2);
      int kof = (lane & 3) << 3;
      GLD16(&A[(size_t)(m0 + row) * 768 + k0 + kof], (char*)As + w * 2048 + c * 1024);
      GLD16(&Bm[(size_t)(n0 + row) * 768 + k0 + kof], (char*)Bs + w * 2048 + c * 1024);
    }
    __syncthreads();
    bf16x8 af[4], bfv[4];
#pragma unroll
    for (int i = 0; i < 4; i++) af[i] = *(const bf16x8*)&As[(wr * 64 + i * 16 + r) * 32 + g * 8];
#pragma unroll
    for (int j = 0; j < 4; j++) bfv[j] = *(const bf16x8*)&Bs[(wc * 64 + j * 16 + r) * 32 + g * 8];
#pragma unroll
    for (int i = 0; i < 4; i++)
#pragma unroll
      for (int j = 0; j < 4; j++)
        acc[i][j] = __builtin_amdgcn_mfma_f32_16x16x32_bf16(af[i], bfv[j], acc[i][j], 0, 0, 0);
    __syncthreads();
  }

#pragma unroll
  for (int i = 0; i < 4; i++) {
#pragma unroll
    for (int j = 0; j < 4; j++) {
      int c = n0 + wc * 64 + j * 16 + r;
#pragma unroll
      for (int e = 0; e < 4; e++) {
        int mrow = m0 + wr * 64 + i * 16 + g * 4 + e;
        float val = acc[i][j][e];
        int which = c / 768;
        int cc = c - which * 768;
        int h = cc >> 6, d = cc & 63;
        int b = mrow >> 10, n = mrow & 1023;
        size_t bh = (size_t)(b * Hh + h);
        if (which == 0)      q_bf[(bh * Nn + n) * HD + d] = (bf16_t)val;
        else if (which == 1) k_bf[(bh * Nn + n) * HD + d] = (bf16_t)val;
        else                 vT_bf[(bh * HD + d) * Nn + n] = (bf16_t)val;
      }
    }
  }
}

// ---------------- generic 128x128 GEMM (MODE 1: proj epilogue) -----------
template <int MODE>
__global__ __launch_bounds__(256) void gemm_bt(
    const bf16_t* __restrict__ A, const bf16_t* __restrict__ Bm, int N, int K,
    float* __restrict__ outF, const float* __restrict__ bias) {
  __shared__ bf16_t As[128 * 40];
  __shared__ bf16_t Bs[128 * 40];
  const int tid = threadIdx.x;
  const int lane = tid & 63;
  const int w = tid >> 6;
  const int wr = w >> 1, wc = w & 1;
  const int g = lane >> 4, r = lane & 15;
  const int ntiles = N >> 7;
  const int m0 = (blockIdx.x / ntiles) << 7;
  const int n0 = (blockIdx.x % ntiles) << 7;

  const f32x4 fz = {0.f, 0.f, 0.f, 0.f};
  f32x4 acc[4][4];
#pragma unroll
  for (int i = 0; i < 4; i++)
#pragma unroll
    for (int j = 0; j < 4; j++) acc[i][j] = fz;

  for (int k0 = 0; k0 < K; k0 += 32) {
#pragma unroll
    for (int p = 0; p < 2; p++) {
      int idx = tid + (p << 8);
      int row = idx >> 2;
      int kof = (idx & 3) << 3;
      *(bf16x8*)&As[row * 40 + kof] = *(const bf16x8*)&A[(size_t)(m0 + row) * K + k0 + kof];
      *(bf16x8*)&Bs[row * 40 + kof] = *(const bf16x8*)&Bm[(size_t)(n0 + row) * K + k0 + kof];
    }
    __syncthreads();
    bf16x8 af[4], bfv[4];
#pragma unroll
    for (int i = 0; i < 4; i++) af[i] = *(const bf16x8*)&As[(wr * 64 + i * 16 + r) * 40 + g * 8];
#pragma unroll
    for (int j = 0; j < 4; j++) bfv[j] = *(const bf16x8*)&Bs[(wc * 64 + j * 16 + r) * 40 + g * 8];
#pragma unroll
    for (int i = 0; i < 4; i++)
#pragma unroll
      for (int j = 0; j < 4; j++)
        acc[i][j] = __builtin_amdgcn_mfma_f32_16x16x32_bf16(af[i], bfv[j], acc[i][j], 0, 0, 0);
    __syncthreads();
  }

#pragma unroll
  for (int i = 0; i < 4; i++) {
#pragma unroll
    for (int j = 0; j < 4; j++) {
      int c = n0 + wc * 64 + j * 16 + r;
#pragma unroll
      for (int e = 0; e < 4; e++) {
        int mrow = m0 + wr * 64 + i * 16 + g * 4 + e;
        outF[(size_t)mrow * N + c] = acc[i][j][e] + bias[c];
      }
    }
  }
}

// ---------------- per-(b,h,n) bias MLP -> {1+b0, b1, -b2/N, 0} -----------
__global__ __launch_bounds__(256) void bias_mlp(
    const bf16_t* __restrict__ qb, const bf16_t* __restrict__ kb,
    const float* __restrict__ w1, const float* __restrict__ b1,
    const float* __restrict__ w2, const float* __restrict__ b2,
    float* __restrict__ bias4) {
  __shared__ float w1s[32 * 129];
  __shared__ float qks[8][128];
  __shared__ float h1s[8][32];
  const int t = threadIdx.x;
#pragma unroll
  for (int p = 0; p < 16; p++) {
    int idx = p * 256 + t;
    w1s[(idx >> 7) * 129 + (idx & 127)] = w1[idx];
  }
  const int rl = t >> 5, u = t & 31;
  const int rowg = blockIdx.x * 8 + rl;
  {
    int i4 = u * 4;
    const bf16_t* src = (i4 < 64) ? (qb + (size_t)rowg * HD + i4)
                                  : (kb + (size_t)rowg * HD + (i4 - 64));
    bf16x4 vv = *(const bf16x4*)src;
#pragma unroll
    for (int z = 0; z < 4; z++) qks[rl][i4 + z] = (float)vv[z];
  }
  __syncthreads();
  float accv = b1[u];
#pragma unroll 8
  for (int i = 0; i < 128; i++) accv += qks[rl][i] * w1s[u * 129 + i];
  h1s[rl][u] = fmaxf(accv, 0.f);
  __syncthreads();
  if (u < 4) {
    float outv = 0.f;
    if (u < 3) {
      float s = b2[u];
#pragma unroll
      for (int j = 0; j < 32; j++) s += w2[u * 32 + j] * h1s[rl][j];
      float v = fabsf(s);
      outv = (u == 0) ? (1.f + v) : ((u == 1) ? v : -v * (1.f / (float)Nn));
    }
    bias4[(size_t)rowg * 4 + u] = outv;
  }
}

// ---------------- fused: QK^T -> softmax -> blend -> cur write -> PV -----
// Round-2 structure + 3 fixes: XCD swizzle, coalesced cur from LDS-bf16,
// launch_bounds(256,4). Block: 256 thr (4 waves), 16 rows of one (b,h).
// P1: wave w computes P cols [256w,+256) in acc[16]; softmax; bf16 P->LDS.
// P2: thread owns 4 cols x 16 rows; 8-batched prev loads; cur float4 write
//     (from bf16 P, round-9-proven); blend; rewrite LDS.
// P3: PV, wave w -> d-cols [16w,+16), 4 indep K-chains from swizzled LDS.
__global__ __launch_bounds__(256, 4) void attn_fused(
    const bf16_t* __restrict__ qb, const bf16_t* __restrict__ kb,
    const bf16_t* __restrict__ vT, const float* __restrict__ prev,
    const float* __restrict__ bias4, float* __restrict__ cur,
    bf16_t* __restrict__ oh) {
  __shared__ char Plb[16 * 2048];   // 16 x 1024 bf16, byte ^= (row&7)<<4
  __shared__ float redmax[16][4];
  __shared__ float redsum[16][4];
  const int bid = blockIdx.x;
  const int tile = (bid & 7) * 384 + (bid >> 3);  // XCD-bijective (3072%8==0)
  const int bh = tile >> 6, mt = tile & 63;
  const int tid = threadIdx.x;
  const int lane = tid & 63, w = tid >> 6;
  const int g = lane >> 4, r = lane & 15;
  const int row0 = mt << 4;

  // ---- Phase 1: QK^T + softmax -> bf16 P in LDS ----
  const bf16_t* qp = qb + ((size_t)bh * Nn + row0) * HD;
  const bf16_t* kp = kb + (size_t)bh * Nn * HD;
  bf16x8 a0 = *(const bf16x8*)&qp[r * HD + g * 8];
  bf16x8 a1 = *(const bf16x8*)&qp[r * HD + g * 8 + 32];
  const f32x4 fz = {0.f, 0.f, 0.f, 0.f};
  f32x4 acc[16];
#pragma unroll
  for (int t = 0; t < 16; t++) {
    int col = (w << 8) + (t << 4) + r;
    bf16x8 b0 = *(const bf16x8*)&kp[(size_t)col * HD + g * 8];
    bf16x8 b1 = *(const bf16x8*)&kp[(size_t)col * HD + g * 8 + 32];
    f32x4 z = __builtin_amdgcn_mfma_f32_16x16x32_bf16(a0, b0, fz, 0, 0, 0);
    acc[t] = __builtin_amdgcn_mfma_f32_16x16x32_bf16(a1, b1, z, 0, 0, 0);
  }
  const float scale = 0.125f;
  float mj[4] = {-3.0e38f, -3.0e38f, -3.0e38f, -3.0e38f};
#pragma unroll
  for (int t = 0; t < 16; t++)
#pragma unroll
    for (int e = 0; e < 4; e++) {
      acc[t][e] *= scale;
      mj[e] = fmaxf(mj[e], acc[t][e]);
    }
#pragma unroll
  for (int s = 1; s < 16; s <<= 1)
#pragma unroll
    for (int e = 0; e < 4; e++) mj[e] = fmaxf(mj[e], __shfl_xor(mj[e], s, 64));
  if (r == 0) {
#pragma unroll
    for (int e = 0; e < 4; e++) redmax[g * 4 + e][w] = mj[e];
  }
  __syncthreads();
  float rm[4];
#pragma unroll
  for (int e = 0; e < 4; e++) {
    float v = fmaxf(redmax[g * 4 + e][0], redmax[g * 4 + e][1]);
    rm[e] = fmaxf(v, fmaxf(redmax[g * 4 + e][2], redmax[g * 4 + e][3]));
  }
  float sj[4] = {0.f, 0.f, 0.f, 0.f};
#pragma unroll
  for (int t = 0; t < 16; t++)
#pragma unroll
    for (int e = 0; e < 4; e++) {
      float ev = __expf(acc[t][e] - rm[e]);
      acc[t][e] = ev;
      sj[e] += ev;
    }
#pragma unroll
  for (int s = 1; s < 16; s <<= 1)
#pragma unroll
    for (int e = 0; e < 4; e++) sj[e] += __shfl_xor(sj[e], s, 64);
  if (r == 0) {
#pragma unroll
    for (int e = 0; e < 4; e++) redsum[g * 4 + e][w] = sj[e];
  }
  __syncthreads();
  float inv[4];
#pragma unroll
  for (int e = 0; e < 4; e++)
    inv[e] = 1.f / (redsum[g * 4 + e][0] + redsum[g * 4 + e][1] +
                    redsum[g * 4 + e][2] + redsum[g * 4 + e][3]);
  // bf16 P -> swizzled LDS
#pragma unroll
  for (int t = 0; t < 16; t++) {
    int col = (w << 8) + (t << 4) + r;
#pragma unroll
    for (int e = 0; e < 4; e++) {
      int row = g * 4 + e;
      int off = (row * 2048 + col * 2) ^ ((row & 7) << 4);
      *(bf16_t*)(Plb + off) = (bf16_t)(acc[t][e] * inv[e]);
    }
  }
  __syncthreads();

  // ---- Phase 2: batched prev loads + coalesced cur write + blend ----
  const int c4 = tid << 2;  // thread's 4-col chunk (0..1023)
  const float* pp = prev + (size_t)bh * Nn * Nn + (size_t)row0 * Nn + c4;
  float* cp = cur + (size_t)bh * Nn * Nn + (size_t)row0 * Nn + c4;
  const float* bp = bias4 + ((size_t)(bh << 10) + row0) * 4;
#pragma unroll
  for (int half = 0; half < 2; half++) {
    float4 pv[8];
#pragma unroll
    for (int i = 0; i < 8; i++)
      pv[i] = *(const float4*)&pp[(size_t)(half * 8 + i) * Nn];
#pragma unroll
    for (int i = 0; i < 8; i++) {
      int row = half * 8 + i;
      int off = (row * 2048 + c4 * 2) ^ ((row & 7) << 4);
      bf16x4 p4 = *(const bf16x4*)(Plb + off);
      float4 pf;
      pf.x = (float)p4[0]; pf.y = (float)p4[1]; pf.z = (float)p4[2]; pf.w = (float)p4[3];
      *(float4*)&cp[(size_t)row * Nn] = pf;   // coalesced cur write
      float4 bv = *(const float4*)&bp[row * 4];
      bf16x4 nb;
      nb[0] = (bf16_t)(bv.x * pf.x + bv.y * pv[i].x + bv.z);
      nb[1] = (bf16_t)(bv.x * pf.y + bv.y * pv[i].y + bv.z);
      nb[2] = (bf16_t)(bv.x * pf.z + bv.y * pv[i].z + bv.z);
      nb[3] = (bf16_t)(bv.x * pf.w + bv.y * pv[i].w + bv.z);
      *(bf16x4*)(Plb + off) = nb;
    }
  }
  __syncthreads();

  // ---- Phase 3: PV. wave w -> d-cols [16w,+16), 4 indep K-chains ----
  const bf16_t* vrow = vT + (size_t)bh * HD * Nn + (size_t)((w << 4) + r) * Nn;
  f32x4 c0 = fz, c1 = fz, c2 = fz, c3 = fz;
#pragma unroll
  for (int ks = 0; ks < 8; ks++) {
    int kA = ks << 5;
    bf16x8 pA = *(const bf16x8*)(Plb + ((r * 2048 + (kA + g * 8) * 2) ^ ((r & 7) << 4)));
    bf16x8 pB = *(const bf16x8*)(Plb + ((r * 2048 + (256 + kA + g * 8) * 2) ^ ((r & 7) << 4)));
    bf16x8 pC = *(const bf16x8*)(Plb + ((r * 2048 + (512 + kA + g * 8) * 2) ^ ((r & 7) << 4)));
    bf16x8 pD = *(const bf16x8*)(Plb + ((r * 2048 + (768 + kA + g * 8) * 2) ^ ((r & 7) << 4)));
    bf16x8 vA = *(const bf16x8*)&vrow[kA + g * 8];
    bf16x8 vB = *(const bf16x8*)&vrow[256 + kA + g * 8];
    bf16x8 vC = *(const bf16x8*)&vrow[512 + kA + g * 8];
    bf16x8 vD = *(const bf16x8*)&vrow[768 + kA + g * 8];
    c0 = __builtin_amdgcn_mfma_f32_16x16x32_bf16(pA, vA, c0, 0, 0, 0);
    c1 = __builtin_amdgcn_mfma_f32_16x16x32_bf16(pB, vB, c1, 0, 0, 0);
    c2 = __builtin_amdgcn_mfma_f32_16x16x32_bf16(pC, vC, c2, 0, 0, 0);
    c3 = __builtin_amdgcn_mfma_f32_16x16x32_bf16(pD, vD, c3, 0, 0, 0);
  }
  f32x4 osum = (c0 + c1) + (c2 + c3);
  const int b = bh / Hh, h = bh % Hh;
#pragma unroll
  for (int e = 0; e < 4; e++) {
    int nrow = row0 + g * 4 + e;
    oh[((size_t)(b * Nn + nrow)) * Cc + h * HD + (w << 4) + r] = (bf16_t)osum[e];
  }
}

// -------------------------------------------------------------------------
extern "C" void kernel_launch(void* const* d_in, const int* in_sizes, int n_in,
                              void* d_out, int out_size, void* d_ws, size_t ws_size,
                              hipStream_t stream) {
  const float* x      = (const float*)d_in[0];
  const float* prev   = (const float*)d_in[1];
  const float* qkv_w  = (const float*)d_in[2];
  const float* proj_w = (const float*)d_in[3];
  const float* proj_b = (const float*)d_in[4];
  const float* bp_w1  = (const float*)d_in[5];
  const float* bp_b1  = (const float*)d_in[6];
  const float* bp_w2  = (const float*)d_in[7];
  const float* bp_w2b = (const float*)d_in[8];

  float* out0 = (float*)d_out;
  float* cur  = out0 + OUT0;

  char* ws = (char*)d_ws;
  bf16_t* xb    = (bf16_t*)(ws + 0);
  bf16_t* qwb   = (bf16_t*)(ws + 6291456);
  bf16_t* pwb   = (bf16_t*)(ws + 9830400);
  bf16_t* qbf   = (bf16_t*)(ws + 11010048);
  bf16_t* kbf   = (bf16_t*)(ws + 17301504);
  bf16_t* vtb   = (bf16_t*)(ws + 23592960);
  float*  bias4 = (float*)(ws + 29884416);
  bf16_t* ohb   = (bf16_t*)(ws + 30670848);
  if (ws_size < 36962304) return;

  convert_all<<<5376, 256, 0, stream>>>(x, qkv_w, proj_w, xb, qwb, pwb);
  gemm_qkv<<<32 * 18, 256, 0, stream>>>(xb, qwb, qbf, kbf, vtb);
  bias_mlp<<<49152 / 8, 256, 0, stream>>>(qbf, kbf, bp_w1, bp_b1, bp_w2, bp_w2b, bias4);
  attn_fused<<<3072, 256, 0, stream>>>(qbf, kbf, vtb, prev, bias4, cur, ohb);
  gemm_bt<1><<<(4096 / 128) * (768 / 128), 256, 0, stream>>>(
      ohb, pwb, 768, 768, out0, proj_b);
}